// Round 9
// baseline (232.141 us; speedup 1.0000x reference)
//
#include <hip/hip_runtime.h>
#include <cstdint>
#include <cmath>

#define B_ 2
#define S_ 2048
#define DIM_ 2048
#define H_ 16
#define HKV_ 4
#define HD_ 128
#define MQ_ (B_*S_)      // 4096 rows
#define NKV_ (HKV_*HD_)  // 512
#define NQKV_ 3072       // fused QKV output width
#define KOFF_ 2048       // col offset of K block in fused buffer
#define VOFF_ 2560       // col offset of V block

typedef unsigned short u16;
typedef unsigned int u32;
typedef __bf16 bf16_t;
typedef bf16_t bf16x8 __attribute__((ext_vector_type(8)));
typedef bf16_t bf16x2 __attribute__((ext_vector_type(2)));
typedef u16 u16x8 __attribute__((ext_vector_type(8)));
typedef u16 u16x4 __attribute__((ext_vector_type(4)));
typedef float f32x4 __attribute__((ext_vector_type(4)));
typedef float f32x16 __attribute__((ext_vector_type(16)));
typedef u32 u32x4 __attribute__((ext_vector_type(4)));

__device__ __forceinline__ u16 f2bf(float f) {
  union { float f; uint32_t u; } v; v.f = f;
  return (u16)((v.u + 0x7FFFu + ((v.u >> 16) & 1u)) >> 16);
}

__device__ __forceinline__ u32 pkbf(float a, float b) {
  bf16x2 v; v[0] = (bf16_t)a; v[1] = (bf16_t)b;
  return __builtin_bit_cast(u32, v);
}

__device__ __forceinline__ float bf2f(u16 u) {
  union { u32 u; float f; } v; v.u = ((u32)u) << 16;
  return v.f;
}

// ---------------- conversion kernels ----------------

__global__ void cvt_x_kernel(const float* __restrict__ in, u16* __restrict__ out, int n4) {
  int i = blockIdx.x * blockDim.x + threadIdx.x;
  if (i >= n4) return;
  float4 v = reinterpret_cast<const float4*>(in)[i];
  u16x4 o;
  o[0] = f2bf(v.x); o[1] = f2bf(v.y); o[2] = f2bf(v.z); o[3] = f2bf(v.w);
  reinterpret_cast<u16x4*>(out)[i] = o;
}

// All four weight transposes in one launch. grid (80, 32).
__global__ void wtT_all_kernel(const float* __restrict__ wq, const float* __restrict__ wk,
                               const float* __restrict__ wv, const float* __restrict__ wo,
                               u16* __restrict__ wqkvT, u16* __restrict__ woT) {
  __shared__ u16 tile[64][66];
  const int z = blockIdx.x;
  const float* src; u16* dst; int N, n0;
  if (z < 32)      { src = wq; dst = wqkvT;                          N = 2048; n0 = z * 64; }
  else if (z < 40) { src = wk; dst = wqkvT + (size_t)KOFF_ * DIM_;   N = 512;  n0 = (z - 32) * 64; }
  else if (z < 48) { src = wv; dst = wqkvT + (size_t)VOFF_ * DIM_;   N = 512;  n0 = (z - 40) * 64; }
  else             { src = wo; dst = woT;                            N = 2048; n0 = (z - 48) * 64; }
  const int k0 = blockIdx.y * 64;
  const int tx = threadIdx.x & 63, ty = threadIdx.x >> 6;
#pragma unroll
  for (int i = 0; i < 16; i++) {
    int kr = ty + i * 4;
    tile[tx][kr] = f2bf(src[(size_t)(k0 + kr) * N + n0 + tx]);
  }
  __syncthreads();
#pragma unroll
  for (int i = 0; i < 16; i++) {
    int nr = ty + i * 4;
    dst[(size_t)(n0 + nr) * DIM_ + k0 + tx] = tile[nr][tx];
  }
}

// RoPE in-place on bf16 fused-QKV buffer; heads 0..15 = Q, 16..19 = K.
__global__ void rope_bf_kernel(u16* __restrict__ buf, const float* __restrict__ cosp,
                               const float* __restrict__ sinp, int npairs) {
  int i = blockIdx.x * blockDim.x + threadIdx.x;
  if (i >= npairs) return;
  int j = i & 63;
  int head = (i >> 6) % 20;
  int token = i / (20 * 64);
  int s = token % S_;
  u16* p = buf + (size_t)token * NQKV_ + head * HD_ + j * 2;
  u32 v = *reinterpret_cast<u32*>(p);
  float t0 = bf2f((u16)(v & 0xFFFF));
  float t1 = bf2f((u16)(v >> 16));
  float c = cosp[s * 64 + j], sn = sinp[s * 64 + j];
  u16 lo = f2bf(t0 * c - t1 * sn);
  u16 hi = f2bf(t0 * sn + t1 * c);
  *reinterpret_cast<u32*>(p) = (u32)lo | ((u32)hi << 16);
}

// Tiled transpose V: fused buf col VOFF_.. -> Vt [b][g][d][s]
__global__ void vtT_kernel(const u16* __restrict__ qkv, u16* __restrict__ vt) {
  __shared__ u16 tile[64][66];
  const int s0 = blockIdx.x * 64, d0 = blockIdx.y * 64;
  const int bg = blockIdx.z, b = bg >> 2, g = bg & 3;
  const int tx = threadIdx.x & 63, ty = threadIdx.x >> 6;
#pragma unroll
  for (int i = 0; i < 16; i++) {
    int sr = ty + i * 4;
    tile[tx][sr] = qkv[(size_t)(b * S_ + s0 + sr) * NQKV_ + VOFF_ + g * HD_ + d0 + tx];
  }
  __syncthreads();
#pragma unroll
  for (int i = 0; i < 16; i++) {
    int dr = ty + i * 4;
    vt[((size_t)bg * HD_ + d0 + dr) * S_ + s0 + tx] = tile[dr][tx];
  }
}

// ---------------- 256x256 8-phase GEMM (with XCD-bijective block swizzle) ----------------
template <typename OutT>
__launch_bounds__(512, 1)
__global__ void gemm256(const u16* __restrict__ A, const u16* __restrict__ Bt,
                        OutT* __restrict__ C, int M, int N, int K) {
  __shared__ u16 As[2][16384];   // [buf] 256 rows x 64 cols
  __shared__ u16 Bs[2][16384];
  const int tid = threadIdx.x;
  const int lane = tid & 63, wid = tid >> 6;
  const int lr = lane & 15, lg = lane >> 4;
  const int wm = (wid >> 2) * 128;   // wave row block
  const int wn = (wid & 3) * 64;     // wave col block

  // T1: XCD-bijective swizzle (nwg % 8 == 0 for both grids used)
  const int nx = gridDim.x;
  const int lin = blockIdx.y * nx + blockIdx.x;
  const int cpx = (nx * gridDim.y) >> 3;
  const int swz = (lin & 7) * cpx + (lin >> 3);
  const int m0 = (swz / nx) * 256, n0 = (swz % nx) * 256;

  const u16* Atile = A + (size_t)m0 * K;
  const u16* Btile = Bt + (size_t)n0 * K;
  const int NT = K >> 6;             // K-tiles of 64 (assumed even)
  const int NIT = NT >> 1;

  f32x4 acc[8][4] = {};
  bf16x8 afr[4][2];
  bf16x8 bfr[2][2][2];

  auto stg = [&](u16* lbase, const u16* gbase, int t, int h) {
#pragma unroll
    for (int j = 0; j < 2; j++) {
      int L = (tid + j * 512) * 16;
      int r = L >> 7;
      int slot = (L >> 4) & 7;
      int c = (slot ^ (r & 7)) << 4;
      const char* src = (const char*)(gbase + (size_t)(h * 128 + r) * K + t * 64) + c;
      __builtin_amdgcn_global_load_lds(
          (const __attribute__((address_space(1))) unsigned int*)src,
          (__attribute__((address_space(3))) unsigned int*)((char*)lbase + h * 16384 + L),
          16, 0, 0);
    }
  };
  auto lds8 = [&](const u16* lbase, int r, int cb) -> bf16x8 {
    int slot = (cb >> 4) & 7;
    int L = r * 128 + ((slot ^ (r & 7)) << 4) + (cb & 15);
    return *reinterpret_cast<const bf16x8*>((const char*)lbase + L);
  };
  auto readA = [&](int buf, int mh) {
#pragma unroll
    for (int im = 0; im < 4; im++)
#pragma unroll
      for (int k = 0; k < 2; k++)
        afr[im][k] = lds8(As[buf], wm + mh * 64 + im * 16 + lr, k * 64 + lg * 16);
  };
  auto readB = [&](int buf, int nh) {
#pragma unroll
    for (int jn = 0; jn < 2; jn++)
#pragma unroll
      for (int k = 0; k < 2; k++)
        bfr[nh][jn][k] = lds8(Bs[buf], wn + nh * 32 + jn * 16 + lr, k * 64 + lg * 16);
  };
  auto quad = [&](int mh, int nh) {
    __builtin_amdgcn_s_setprio(1);
#pragma unroll
    for (int im = 0; im < 4; im++)
#pragma unroll
      for (int jn = 0; jn < 2; jn++)
#pragma unroll
      for (int k = 0; k < 2; k++)
        acc[mh * 4 + im][nh * 2 + jn] = __builtin_amdgcn_mfma_f32_16x16x32_bf16(
            afr[im][k], bfr[nh][jn][k], acc[mh * 4 + im][nh * 2 + jn], 0, 0, 0);
    __builtin_amdgcn_s_setprio(0);
  };
  auto bar = [&]() {
    asm volatile("" ::: "memory");
    __builtin_amdgcn_s_barrier();
    asm volatile("" ::: "memory");
  };

  stg(As[0], Atile, 0, 0); stg(As[0], Atile, 0, 1);
  stg(Bs[0], Btile, 0, 0); stg(Bs[0], Btile, 0, 1);
  stg(As[1], Atile, 1, 0);
  asm volatile("s_waitcnt vmcnt(2)" ::: "memory");
  __builtin_amdgcn_s_barrier();

  for (int it = 0; it < NIT; ++it) {
    const int ta = 2 * it, tb = ta + 1;
    const bool sA = (ta + 2 < NT);
    const bool sB = (tb + 2 < NT);

    readA(0, 0); readB(0, 0);
    stg(As[1], Atile, tb, 1);
    bar(); quad(0, 0); bar();
    readB(0, 1);
    stg(Bs[1], Btile, tb, 0);
    bar(); quad(0, 1); bar();
    readA(0, 1);
    stg(Bs[1], Btile, tb, 1);
    bar(); quad(1, 1); bar();
    if (sA) stg(As[0], Atile, ta + 2, 0);
    bar(); quad(1, 0);
    if (sA) asm volatile("s_waitcnt vmcnt(2)" ::: "memory");
    else    asm volatile("s_waitcnt vmcnt(0)" ::: "memory");
    bar();

    readA(1, 0); readB(1, 0);
    if (sA) stg(As[0], Atile, ta + 2, 1);
    bar(); quad(0, 0); bar();
    readB(1, 1);
    if (sA) stg(Bs[0], Btile, ta + 2, 0);
    bar(); quad(0, 1); bar();
    readA(1, 1);
    if (sA) stg(Bs[0], Btile, ta + 2, 1);
    bar(); quad(1, 1); bar();
    if (sB) stg(As[1], Atile, tb + 2, 0);
    bar(); quad(1, 0);
    if (sA) {
      if (sB) asm volatile("s_waitcnt vmcnt(2)" ::: "memory");
      else    asm volatile("s_waitcnt vmcnt(0)" ::: "memory");
    }
    bar();
  }

#pragma unroll
  for (int i = 0; i < 8; i++)
#pragma unroll
    for (int j = 0; j < 4; j++)
#pragma unroll
      for (int rr = 0; rr < 4; rr++) {
        int row = m0 + wm + (i >> 2) * 64 + (i & 3) * 16 + lg * 4 + rr;
        int col = n0 + wn + (j >> 1) * 32 + (j & 1) * 16 + lr;
        if constexpr (__is_same(OutT, float))
          C[(size_t)row * N + col] = acc[i][j][rr];
        else
          C[(size_t)row * N + col] = f2bf(acc[i][j][rr]);
      }
}

// ---------------- flash attention (v4 + QK chain-split + setprio) ----------------
__launch_bounds__(256, 2)
__global__ void attn_kernel(const u16* __restrict__ Qc, const u16* __restrict__ Kc,
                            const u16* __restrict__ Vt, u16* __restrict__ Ab) {
  __shared__ u16 Ks[2][64 * 128];   // [key][d] 256B rows, 16-slot swizzle
  __shared__ u16 Vs[2][128 * 64];   // [d][key] 128B rows, 8-slot swizzle

  const int bk = blockIdx.x;
  const int i = bk >> 3, gb = bk & 7;
  const int g = gb & 3, b = gb >> 2;
  const int qt = (i < 32) ? (63 - i) : (i - 32);  // heavy-first, complementary pairs
  const int w = threadIdx.x >> 6, lane = threadIdx.x & 63;
  const int l31 = lane & 31, hi = lane >> 5;
  const int h = g * 4 + w;                        // wave = head within group
  const int qbase = qt * 32;
  const int qi = qbase + l31;
  const float k1 = 0.08838834764831845f * 1.4426950408889634f; // scale*log2e

  bf16x8 qf[8];
  const u16* qptr = Qc + (size_t)(b * S_ + qi) * NQKV_ + h * HD_ + hi * 8;
#pragma unroll
  for (int dk = 0; dk < 8; dk++)
    qf[dk] = *reinterpret_cast<const bf16x8*>(qptr + dk * 16);

  f32x16 oacc[4] = {};
  float m = -INFINITY, li = 0.f;

  const char* kgb = (const char*)(Kc + (size_t)b * S_ * NQKV_ + g * HD_);
  const char* vgb = (const char*)(Vt + ((size_t)(b * HKV_ + g) * HD_) * (size_t)S_);
  const int nc = (qt >> 1) + 1;

  auto stage = [&](int buf, int kc) {
#pragma unroll
    for (int j = 0; j < 4; j++) {            // K: 16KB, wave's 4x1KB slices
      int L = (w * 4 + j) * 1024 + lane * 16;
      int key = L >> 8;
      int slot = (L >> 4) & 15;
      const char* src = kgb + (size_t)(kc + key) * (NQKV_ * 2) + ((slot ^ (key & 15)) << 4);
      __builtin_amdgcn_global_load_lds(
          (const __attribute__((address_space(1))) unsigned int*)src,
          (__attribute__((address_space(3))) unsigned int*)((char*)&Ks[buf][0] + (w * 4 + j) * 1024),
          16, 0, 0);
    }
#pragma unroll
    for (int j = 0; j < 4; j++) {            // V: 16KB
      int L = (w * 4 + j) * 1024 + lane * 16;
      int d = L >> 7;
      int slot = (L >> 4) & 7;
      const char* src = vgb + ((size_t)d * S_ + kc) * 2 + ((slot ^ (d & 7)) << 4);
      __builtin_amdgcn_global_load_lds(
          (const __attribute__((address_space(1))) unsigned int*)src,
          (__attribute__((address_space(3))) unsigned int*)((char*)&Vs[buf][0] + (w * 4 + j) * 1024),
          16, 0, 0);
    }
  };

  stage(0, 0);
  if (nc > 1) stage(1, 64);

  for (int c = 0; c < nc; ++c) {
    if (c + 1 < nc) asm volatile("s_waitcnt vmcnt(8)" ::: "memory");
    else            asm volatile("s_waitcnt vmcnt(0)" ::: "memory");
    __builtin_amdgcn_s_barrier();

    const char* kb_l = (const char*)&Ks[c & 1][0];
    const char* vb_l = (const char*)&Vs[c & 1][0];
    const int kc = c * 64;

    // QK swapped, chain-split 2x4-deep per 32-key slab (latency)
    f32x16 s0a = {}, s0b = {}, s1a = {}, s1b = {};
    const int key1 = 32 + l31;
    __builtin_amdgcn_s_setprio(1);
#pragma unroll
    for (int dk = 0; dk < 4; dk++) {
      bf16x8 ka = *reinterpret_cast<const bf16x8*>(kb_l + l31 * 256 + (((dk * 2 + hi) ^ (l31 & 15)) << 4));
      bf16x8 kb = *reinterpret_cast<const bf16x8*>(kb_l + l31 * 256 + ((((dk + 4) * 2 + hi) ^ (l31 & 15)) << 4));
      s0a = __builtin_amdgcn_mfma_f32_32x32x16_bf16(ka, qf[dk], s0a, 0, 0, 0);
      s0b = __builtin_amdgcn_mfma_f32_32x32x16_bf16(kb, qf[dk + 4], s0b, 0, 0, 0);
    }
#pragma unroll
    for (int dk = 0; dk < 4; dk++) {
      bf16x8 ka = *reinterpret_cast<const bf16x8*>(kb_l + key1 * 256 + (((dk * 2 + hi) ^ (key1 & 15)) << 4));
      bf16x8 kb = *reinterpret_cast<const bf16x8*>(kb_l + key1 * 256 + ((((dk + 4) * 2 + hi) ^ (key1 & 15)) << 4));
      s1a = __builtin_amdgcn_mfma_f32_32x32x16_bf16(ka, qf[dk], s1a, 0, 0, 0);
      s1b = __builtin_amdgcn_mfma_f32_32x32x16_bf16(kb, qf[dk + 4], s1b, 0, 0, 0);
    }
    __builtin_amdgcn_s_setprio(0);
    f32x16 sa0 = s0a + s0b;
    f32x16 sa1 = s1a + s1b;

    float t0[16], t1[16];
    const bool edge = (kc + 63 > qbase);
#pragma unroll
    for (int r = 0; r < 16; r++) {
      int kl = (r & 3) + 8 * (r >> 2) + 4 * hi;
      float v0 = sa0[r] * k1;
      float v1 = sa1[r] * k1;
      if (edge) {
        v0 = (kc + kl <= qi) ? v0 : -INFINITY;
        v1 = (kc + 32 + kl <= qi) ? v1 : -INFINITY;
      }
      t0[r] = v0; t1[r] = v1;
    }

    float mx[8];
#pragma unroll
    for (int r = 0; r < 8; r++)
      mx[r] = fmaxf(fmaxf(t0[r], t0[r + 8]), fmaxf(t1[r], t1[r + 8]));
    mx[0] = fmaxf(mx[0], mx[4]); mx[1] = fmaxf(mx[1], mx[5]);
    mx[2] = fmaxf(mx[2], mx[6]); mx[3] = fmaxf(mx[3], mx[7]);
    mx[0] = fmaxf(fmaxf(mx[0], mx[1]), fmaxf(mx[2], mx[3]));
    float tm = fmaxf(mx[0], __shfl_xor(mx[0], 32));

    if (!__all(tm <= m + 8.f)) {               // defer-max (T13)
      float mnew = fmaxf(m, tm);
      float corr = __builtin_amdgcn_exp2f(m - mnew);
      li *= corr;
#pragma unroll
      for (int r = 0; r < 16; r++) {
        float cc = __shfl(corr, (r & 3) + 8 * (r >> 2) + 4 * hi);
#pragma unroll
        for (int df = 0; df < 4; df++) oacc[df][r] *= cc;
      }
      m = mnew;
    }

    u32 own0[8], own1[8], oth0[8], oth1[8];
    float ps = 0.f;
#pragma unroll
    for (int s = 0; s < 8; s++) {
      float a0 = __builtin_amdgcn_exp2f(t0[2 * s] - m);
      float b0 = __builtin_amdgcn_exp2f(t0[2 * s + 1] - m);
      float a1 = __builtin_amdgcn_exp2f(t1[2 * s] - m);
      float b1 = __builtin_amdgcn_exp2f(t1[2 * s + 1] - m);
      ps += (a0 + b0) + (a1 + b1);
      own0[s] = pkbf(a0, b0);
      own1[s] = pkbf(a1, b1);
    }
    ps += __shfl_xor(ps, 32);
    li += ps;
#pragma unroll
    for (int s = 0; s < 8; s++) {
      oth0[s] = (u32)__shfl_xor((int)own0[s], 32);
      oth1[s] = (u32)__shfl_xor((int)own1[s], 32);
    }

    __builtin_amdgcn_s_setprio(1);
#pragma unroll
    for (int ks = 0; ks < 4; ks++) {
      const u32* ow = (ks < 2) ? own0 : own1;
      const u32* ot = (ks < 2) ? oth0 : oth1;
      const int bo = 4 * (ks & 1);
      u32x4 pw;
      pw[0] = hi ? ot[bo + 2] : ow[bo];
      pw[1] = hi ? ot[bo + 3] : ow[bo + 1];
      pw[2] = hi ? ow[bo + 2] : ot[bo];
      pw[3] = hi ? ow[bo + 3] : ot[bo + 1];
      bf16x8 pf = __builtin_bit_cast(bf16x8, pw);
#pragma unroll
      for (int df = 0; df < 4; df++) {
        int d = df * 32 + l31;
        bf16x8 vf = *reinterpret_cast<const bf16x8*>(vb_l + d * 128 + (((ks * 2 + hi) ^ (d & 7)) << 4));
        oacc[df] = __builtin_amdgcn_mfma_f32_32x32x16_bf16(pf, vf, oacc[df], 0, 0, 0);
      }
    }
    __builtin_amdgcn_s_setprio(0);

    __builtin_amdgcn_s_barrier();
    if (c + 2 < nc) stage(c & 1, kc + 128);
  }

#pragma unroll
  for (int r = 0; r < 16; r++) {
    int qrow = (r & 3) + 8 * (r >> 2) + 4 * hi;
    float lsum = __shfl(li, qrow);
    float inv = 1.f / lsum;
    u16* orow = Ab + ((size_t)((b * S_ + qbase + qrow) * H_ + h)) * HD_ + l31;
#pragma unroll
    for (int df = 0; df < 4; df++)
      orow[df * 32] = f2bf(oacc[df][r] * inv);
  }
}

// ---------------- launch ----------------
extern "C" void kernel_launch(void* const* d_in, const int* in_sizes, int n_in,
                              void* d_out, int out_size, void* d_ws, size_t ws_size,
                              hipStream_t stream) {
  const float* x    = (const float*)d_in[0];
  const float* cosp = (const float*)d_in[1];
  const float* sinp = (const float*)d_in[2];
  const float* wq   = (const float*)d_in[3];
  const float* wk   = (const float*)d_in[4];
  const float* wv   = (const float*)d_in[5];
  const float* wo   = (const float*)d_in[6];
  float* out = (float*)d_out;

  char* ws = (char*)d_ws;
  size_t off = 0;
  auto alloc = [&](size_t bytes) -> void* {
    void* p = ws + off;
    off += (bytes + 255) & ~(size_t)255;
    return p;
  };
  u16* xb     = (u16*)alloc((size_t)MQ_ * DIM_ * 2);
  u16* wqkvT  = (u16*)alloc((size_t)NQKV_ * DIM_ * 2);
  u16* woT    = (u16*)alloc((size_t)DIM_ * DIM_ * 2);
  u16* Cq     = (u16*)alloc((size_t)MQ_ * NQKV_ * 2);   // fused QKV (bf16)
  u16* Vt     = (u16*)alloc((size_t)MQ_ * NKV_ * 2);
  u16* Ab     = (u16*)alloc((size_t)MQ_ * DIM_ * 2);

  const int TB = 256;
  cvt_x_kernel<<<(MQ_ * DIM_ / 4 + TB - 1) / TB, TB, 0, stream>>>(x, xb, MQ_ * DIM_ / 4);
  wtT_all_kernel<<<dim3(80, 32), TB, 0, stream>>>(wq, wk, wv, wo, wqkvT, woT);

  // fused QKV projection (bf16 out): 256x256 8-phase
  gemm256<u16><<<dim3(NQKV_ / 256, MQ_ / 256), 512, 0, stream>>>(xb, wqkvT, Cq, MQ_, NQKV_, DIM_);

  // RoPE in-place on Q+K blocks (heads 0..19); V transpose
  rope_bf_kernel<<<(MQ_ * 20 * 64 + TB - 1) / TB, TB, 0, stream>>>(Cq, cosp, sinp, MQ_ * 20 * 64);
  vtT_kernel<<<dim3(S_ / 64, HD_ / 64, B_ * HKV_), TB, 0, stream>>>(Cq, Vt);

  // attention: 512 blocks = 64 q-tiles x 4 groups x 2 batch
  attn_kernel<<<dim3(64 * 8), TB, 0, stream>>>(Cq, Cq + KOFF_, Vt, Ab);

  // output projection -> f32 d_out: 256x256 8-phase
  gemm256<float><<<dim3(DIM_ / 256, MQ_ / 256), 512, 0, stream>>>(Ab, woT, out, MQ_, DIM_, DIM_);
}

// Round 10
// 210.014 us; speedup vs baseline: 1.1054x; 1.1054x over previous
//
#include <hip/hip_runtime.h>
#include <cstdint>
#include <cmath>

#define B_ 2
#define S_ 2048
#define DIM_ 2048
#define H_ 16
#define HKV_ 4
#define HD_ 128
#define MQ_ (B_*S_)      // 4096 rows
#define NKV_ (HKV_*HD_)  // 512
#define NQKV_ 3072       // fused QKV output width
#define KOFF_ 2048       // col offset of K block in fused buffer
#define VOFF_ 2560       // col offset of V block

typedef unsigned short u16;
typedef unsigned int u32;
typedef __bf16 bf16_t;
typedef bf16_t bf16x8 __attribute__((ext_vector_type(8)));
typedef bf16_t bf16x2 __attribute__((ext_vector_type(2)));
typedef u16 u16x8 __attribute__((ext_vector_type(8)));
typedef u16 u16x4 __attribute__((ext_vector_type(4)));
typedef float f32x4 __attribute__((ext_vector_type(4)));
typedef float f32x16 __attribute__((ext_vector_type(16)));
typedef u32 u32x4 __attribute__((ext_vector_type(4)));

__device__ __forceinline__ u16 f2bf(float f) {
  union { float f; uint32_t u; } v; v.f = f;
  return (u16)((v.u + 0x7FFFu + ((v.u >> 16) & 1u)) >> 16);
}

__device__ __forceinline__ u32 pkbf(float a, float b) {
  bf16x2 v; v[0] = (bf16_t)a; v[1] = (bf16_t)b;
  return __builtin_bit_cast(u32, v);
}

__device__ __forceinline__ float bf2f(u16 u) {
  union { u32 u; float f; } v; v.u = ((u32)u) << 16;
  return v.f;
}

// ---------------- conversion kernels ----------------

__global__ void cvt_x_kernel(const float* __restrict__ in, u16* __restrict__ out, int n4) {
  int i = blockIdx.x * blockDim.x + threadIdx.x;
  if (i >= n4) return;
  float4 v = reinterpret_cast<const float4*>(in)[i];
  u16x4 o;
  o[0] = f2bf(v.x); o[1] = f2bf(v.y); o[2] = f2bf(v.z); o[3] = f2bf(v.w);
  reinterpret_cast<u16x4*>(out)[i] = o;
}

// All four weight transposes in one launch. grid (80, 32).
__global__ void wtT_all_kernel(const float* __restrict__ wq, const float* __restrict__ wk,
                               const float* __restrict__ wv, const float* __restrict__ wo,
                               u16* __restrict__ wqkvT, u16* __restrict__ woT) {
  __shared__ u16 tile[64][66];
  const int z = blockIdx.x;
  const float* src; u16* dst; int N, n0;
  if (z < 32)      { src = wq; dst = wqkvT;                          N = 2048; n0 = z * 64; }
  else if (z < 40) { src = wk; dst = wqkvT + (size_t)KOFF_ * DIM_;   N = 512;  n0 = (z - 32) * 64; }
  else if (z < 48) { src = wv; dst = wqkvT + (size_t)VOFF_ * DIM_;   N = 512;  n0 = (z - 40) * 64; }
  else             { src = wo; dst = woT;                            N = 2048; n0 = (z - 48) * 64; }
  const int k0 = blockIdx.y * 64;
  const int tx = threadIdx.x & 63, ty = threadIdx.x >> 6;
#pragma unroll
  for (int i = 0; i < 16; i++) {
    int kr = ty + i * 4;
    tile[tx][kr] = f2bf(src[(size_t)(k0 + kr) * N + n0 + tx]);
  }
  __syncthreads();
#pragma unroll
  for (int i = 0; i < 16; i++) {
    int nr = ty + i * 4;
    dst[(size_t)(n0 + nr) * DIM_ + k0 + tx] = tile[nr][tx];
  }
}

// RoPE in-place on bf16 fused-QKV buffer; heads 0..15 = Q, 16..19 = K.
__global__ void rope_bf_kernel(u16* __restrict__ buf, const float* __restrict__ cosp,
                               const float* __restrict__ sinp, int npairs) {
  int i = blockIdx.x * blockDim.x + threadIdx.x;
  if (i >= npairs) return;
  int j = i & 63;
  int head = (i >> 6) % 20;
  int token = i / (20 * 64);
  int s = token % S_;
  u16* p = buf + (size_t)token * NQKV_ + head * HD_ + j * 2;
  u32 v = *reinterpret_cast<u32*>(p);
  float t0 = bf2f((u16)(v & 0xFFFF));
  float t1 = bf2f((u16)(v >> 16));
  float c = cosp[s * 64 + j], sn = sinp[s * 64 + j];
  u16 lo = f2bf(t0 * c - t1 * sn);
  u16 hi = f2bf(t0 * sn + t1 * c);
  *reinterpret_cast<u32*>(p) = (u32)lo | ((u32)hi << 16);
}

// Tiled transpose V: fused buf col VOFF_.. -> Vt [b][g][d][s]
__global__ void vtT_kernel(const u16* __restrict__ qkv, u16* __restrict__ vt) {
  __shared__ u16 tile[64][66];
  const int s0 = blockIdx.x * 64, d0 = blockIdx.y * 64;
  const int bg = blockIdx.z, b = bg >> 2, g = bg & 3;
  const int tx = threadIdx.x & 63, ty = threadIdx.x >> 6;
#pragma unroll
  for (int i = 0; i < 16; i++) {
    int sr = ty + i * 4;
    tile[tx][sr] = qkv[(size_t)(b * S_ + s0 + sr) * NQKV_ + VOFF_ + g * HD_ + d0 + tx];
  }
  __syncthreads();
#pragma unroll
  for (int i = 0; i < 16; i++) {
    int dr = ty + i * 4;
    vt[((size_t)bg * HD_ + d0 + dr) * S_ + s0 + tx] = tile[dr][tx];
  }
}

// ---------------- 256xBN 8-phase GEMM (BN in {256,128}) ----------------
// C(MxN) = A(bf16 MxK) x Bt(bf16 NxK)^T. 512 threads = 8 waves.
// BN=256: waves 2M x 4N, per-wave 128x64. BN=128: waves 4M x 2N, per-wave 64x64.
// BK=64, 2 K-tiles/iter. 3-bit slot swizzle (slot ^= row&7), pre-swizzled source.
// Counted vmcnt(2) at phases 4/8 only (per-tile outstanding ops: 2 newest allowed).
template <int BN, typename OutT>
__launch_bounds__(512, 1)
__global__ void gemm256(const u16* __restrict__ A, const u16* __restrict__ Bt,
                        OutT* __restrict__ C, int M, int N, int K) {
  constexpr int NWN = BN / 64;        // N-waves (4 or 2)
  constexpr int NWM = 8 / NWN;        // M-waves (2 or 4)
  constexpr int RW  = 256 / NWM;      // rows per wave (128 or 64)
  constexpr int RH  = RW / 2;         // rows per mh half (64 or 32)
  constexpr int MFR = RH / 16;        // m-frags per half (4 or 2)
  constexpr int BHB = BN * 64;        // B half bytes (16384 or 8192)
  constexpr int BST = BHB / 8192;     // B stage steps (2 or 1)

  __shared__ u16 As[2][16384];        // 256 rows x 64 cols
  __shared__ u16 Bs[2][BN * 64];
  const int tid = threadIdx.x;
  const int lane = tid & 63, wid = tid >> 6;
  const int lr = lane & 15, lg = lane >> 4;
  const int wm = (wid / NWN) * RW;
  const int wn = (wid % NWN) * 64;
  const int m0 = blockIdx.y * 256, n0 = blockIdx.x * BN;
  const u16* Atile = A + (size_t)m0 * K;
  const u16* Btile = Bt + (size_t)n0 * K;
  const int NT = K >> 6;
  const int NIT = NT >> 1;

  f32x4 acc[2 * MFR][4] = {};
  bf16x8 afr[MFR][2];
  bf16x8 bfr[2][2][2];

  auto stgA = [&](u16* lbase, int t, int h) {
#pragma unroll
    for (int j = 0; j < 2; j++) {
      int L = (tid + j * 512) * 16;
      int r = L >> 7;
      int slot = (L >> 4) & 7;
      int c = (slot ^ (r & 7)) << 4;
      const char* src = (const char*)(Atile + (size_t)(h * 128 + r) * K + t * 64) + c;
      __builtin_amdgcn_global_load_lds(
          (const __attribute__((address_space(1))) unsigned int*)src,
          (__attribute__((address_space(3))) unsigned int*)((char*)lbase + h * 16384 + L),
          16, 0, 0);
    }
  };
  auto stgB = [&](u16* lbase, int t, int h) {
#pragma unroll
    for (int j = 0; j < BST; j++) {
      int L = (tid + j * 512) * 16;
      int r = L >> 7;
      int slot = (L >> 4) & 7;
      int c = (slot ^ (r & 7)) << 4;
      const char* src = (const char*)(Btile + (size_t)(h * (BN / 2) + r) * K + t * 64) + c;
      __builtin_amdgcn_global_load_lds(
          (const __attribute__((address_space(1))) unsigned int*)src,
          (__attribute__((address_space(3))) unsigned int*)((char*)lbase + h * BHB + L),
          16, 0, 0);
    }
  };
  auto lds8 = [&](const u16* lbase, int r, int cb) -> bf16x8 {
    int slot = (cb >> 4) & 7;
    int L = r * 128 + ((slot ^ (r & 7)) << 4) + (cb & 15);
    return *reinterpret_cast<const bf16x8*>((const char*)lbase + L);
  };
  auto readA = [&](int buf, int mh) {
#pragma unroll
    for (int im = 0; im < MFR; im++)
#pragma unroll
      for (int k = 0; k < 2; k++)
        afr[im][k] = lds8(As[buf], wm + mh * RH + im * 16 + lr, k * 64 + lg * 16);
  };
  auto readB = [&](int buf, int nh) {
#pragma unroll
    for (int jn = 0; jn < 2; jn++)
#pragma unroll
      for (int k = 0; k < 2; k++)
        bfr[nh][jn][k] = lds8(Bs[buf], wn + nh * 32 + jn * 16 + lr, k * 64 + lg * 16);
  };
  auto quad = [&](int mh, int nh) {
    __builtin_amdgcn_s_setprio(1);
#pragma unroll
    for (int im = 0; im < MFR; im++)
#pragma unroll
      for (int jn = 0; jn < 2; jn++)
#pragma unroll
      for (int k = 0; k < 2; k++)
        acc[mh * MFR + im][nh * 2 + jn] = __builtin_amdgcn_mfma_f32_16x16x32_bf16(
            afr[im][k], bfr[nh][jn][k], acc[mh * MFR + im][nh * 2 + jn], 0, 0, 0);
    __builtin_amdgcn_s_setprio(0);
  };
  auto bar = [&]() {
    asm volatile("" ::: "memory");
    __builtin_amdgcn_s_barrier();
    asm volatile("" ::: "memory");
  };

  // prologue: tile0 fully, then S1(t1)=A h0 -> buf1; wait tile0
  stgA(As[0], 0, 0); stgA(As[0], 0, 1);
  stgB(Bs[0], 0, 0); stgB(Bs[0], 0, 1);
  stgA(As[1], 1, 0);
  asm volatile("s_waitcnt vmcnt(2)" ::: "memory");
  __builtin_amdgcn_s_barrier();

  for (int it = 0; it < NIT; ++it) {
    const int ta = 2 * it, tb = ta + 1;
    const bool sA = (ta + 2 < NT);
    const bool sB = (tb + 2 < NT);

    readA(0, 0); readB(0, 0);
    stgA(As[1], tb, 1);
    bar(); quad(0, 0); bar();
    readB(0, 1);
    stgB(Bs[1], tb, 0);
    bar(); quad(0, 1); bar();
    readA(0, 1);
    stgB(Bs[1], tb, 1);
    bar(); quad(1, 1); bar();
    if (sA) stgA(As[0], ta + 2, 0);
    bar(); quad(1, 0);
    if (sA) asm volatile("s_waitcnt vmcnt(2)" ::: "memory");
    else    asm volatile("s_waitcnt vmcnt(0)" ::: "memory");
    bar();

    readA(1, 0); readB(1, 0);
    if (sA) stgA(As[0], ta + 2, 1);
    bar(); quad(0, 0); bar();
    readB(1, 1);
    if (sA) stgB(Bs[0], ta + 2, 0);
    bar(); quad(0, 1); bar();
    readA(1, 1);
    if (sA) stgB(Bs[0], ta + 2, 1);
    bar(); quad(1, 1); bar();
    if (sB) stgA(As[1], tb + 2, 0);
    bar(); quad(1, 0);
    if (sA) {
      if (sB) asm volatile("s_waitcnt vmcnt(2)" ::: "memory");
      else    asm volatile("s_waitcnt vmcnt(0)" ::: "memory");
    }
    bar();
  }

#pragma unroll
  for (int i = 0; i < 2 * MFR; i++)
#pragma unroll
    for (int j = 0; j < 4; j++)
#pragma unroll
      for (int rr = 0; rr < 4; rr++) {
        int row = m0 + wm + (i / MFR) * RH + (i % MFR) * 16 + lg * 4 + rr;
        int col = n0 + wn + (j >> 1) * 32 + (j & 1) * 16 + lr;
        if constexpr (__is_same(OutT, float))
          C[(size_t)row * N + col] = acc[i][j][rr];
        else
          C[(size_t)row * N + col] = f2bf(acc[i][j][rr]);
      }
}

// ---------------- flash attention (round-7 exact: best measured 83 us) ----------------
__launch_bounds__(256, 2)
__global__ void attn_kernel(const u16* __restrict__ Qc, const u16* __restrict__ Kc,
                            const u16* __restrict__ Vt, u16* __restrict__ Ab) {
  __shared__ u16 Ks[2][64 * 128];   // [key][d] 256B rows, 16-slot swizzle
  __shared__ u16 Vs[2][128 * 64];   // [d][key] 128B rows, 8-slot swizzle

  const int bk = blockIdx.x;
  const int i = bk >> 3, gb = bk & 7;
  const int g = gb & 3, b = gb >> 2;
  const int qt = (i < 32) ? (63 - i) : (i - 32);  // heavy-first, complementary pairs
  const int w = threadIdx.x >> 6, lane = threadIdx.x & 63;
  const int l31 = lane & 31, hi = lane >> 5;
  const int h = g * 4 + w;                        // wave = head within group
  const int qbase = qt * 32;
  const int qi = qbase + l31;
  const float k1 = 0.08838834764831845f * 1.4426950408889634f; // scale*log2e

  bf16x8 qf[8];
  const u16* qptr = Qc + (size_t)(b * S_ + qi) * NQKV_ + h * HD_ + hi * 8;
#pragma unroll
  for (int dk = 0; dk < 8; dk++)
    qf[dk] = *reinterpret_cast<const bf16x8*>(qptr + dk * 16);

  f32x16 oacc[4] = {};
  float m = -INFINITY, li = 0.f;

  const char* kgb = (const char*)(Kc + (size_t)b * S_ * NQKV_ + g * HD_);
  const char* vgb = (const char*)(Vt + ((size_t)(b * HKV_ + g) * HD_) * (size_t)S_);
  const int nc = (qt >> 1) + 1;

  auto stage = [&](int buf, int kc) {
#pragma unroll
    for (int j = 0; j < 4; j++) {            // K: 16KB, wave's 4x1KB slices
      int L = (w * 4 + j) * 1024 + lane * 16;
      int key = L >> 8;
      int slot = (L >> 4) & 15;
      const char* src = kgb + (size_t)(kc + key) * (NQKV_ * 2) + ((slot ^ (key & 15)) << 4);
      __builtin_amdgcn_global_load_lds(
          (const __attribute__((address_space(1))) unsigned int*)src,
          (__attribute__((address_space(3))) unsigned int*)((char*)&Ks[buf][0] + (w * 4 + j) * 1024),
          16, 0, 0);
    }
#pragma unroll
    for (int j = 0; j < 4; j++) {            // V: 16KB
      int L = (w * 4 + j) * 1024 + lane * 16;
      int d = L >> 7;
      int slot = (L >> 4) & 7;
      const char* src = vgb + ((size_t)d * S_ + kc) * 2 + ((slot ^ (d & 7)) << 4);
      __builtin_amdgcn_global_load_lds(
          (const __attribute__((address_space(1))) unsigned int*)src,
          (__attribute__((address_space(3))) unsigned int*)((char*)&Vs[buf][0] + (w * 4 + j) * 1024),
          16, 0, 0);
    }
  };

  stage(0, 0);
  if (nc > 1) stage(1, 64);

  for (int c = 0; c < nc; ++c) {
    if (c + 1 < nc) asm volatile("s_waitcnt vmcnt(8)" ::: "memory");
    else            asm volatile("s_waitcnt vmcnt(0)" ::: "memory");
    __builtin_amdgcn_s_barrier();

    const char* kb_l = (const char*)&Ks[c & 1][0];
    const char* vb_l = (const char*)&Vs[c & 1][0];
    const int kc = c * 64;

    f32x16 sa0 = {}, sa1 = {};
#pragma unroll
    for (int dk = 0; dk < 8; dk++) {
      bf16x8 kf0 = *reinterpret_cast<const bf16x8*>(kb_l + l31 * 256 + (((dk * 2 + hi) ^ (l31 & 15)) << 4));
      sa0 = __builtin_amdgcn_mfma_f32_32x32x16_bf16(kf0, qf[dk], sa0, 0, 0, 0);
    }
#pragma unroll
    for (int dk = 0; dk < 8; dk++) {
      int key1 = 32 + l31;
      bf16x8 kf1 = *reinterpret_cast<const bf16x8*>(kb_l + key1 * 256 + (((dk * 2 + hi) ^ (key1 & 15)) << 4));
      sa1 = __builtin_amdgcn_mfma_f32_32x32x16_bf16(kf1, qf[dk], sa1, 0, 0, 0);
    }

    float t0[16], t1[16];
    const bool edge = (kc + 63 > qbase);
#pragma unroll
    for (int r = 0; r < 16; r++) {
      int kl = (r & 3) + 8 * (r >> 2) + 4 * hi;
      float v0 = sa0[r] * k1;
      float v1 = sa1[r] * k1;
      if (edge) {
        v0 = (kc + kl <= qi) ? v0 : -INFINITY;
        v1 = (kc + 32 + kl <= qi) ? v1 : -INFINITY;
      }
      t0[r] = v0; t1[r] = v1;
    }

    float mx[8];
#pragma unroll
    for (int r = 0; r < 8; r++)
      mx[r] = fmaxf(fmaxf(t0[r], t0[r + 8]), fmaxf(t1[r], t1[r + 8]));
    mx[0] = fmaxf(mx[0], mx[4]); mx[1] = fmaxf(mx[1], mx[5]);
    mx[2] = fmaxf(mx[2], mx[6]); mx[3] = fmaxf(mx[3], mx[7]);
    mx[0] = fmaxf(fmaxf(mx[0], mx[1]), fmaxf(mx[2], mx[3]));
    float tm = fmaxf(mx[0], __shfl_xor(mx[0], 32));

    if (!__all(tm <= m + 8.f)) {               // defer-max (T13)
      float mnew = fmaxf(m, tm);
      float corr = __builtin_amdgcn_exp2f(m - mnew);
      li *= corr;
#pragma unroll
      for (int r = 0; r < 16; r++) {
        float cc = __shfl(corr, (r & 3) + 8 * (r >> 2) + 4 * hi);
#pragma unroll
        for (int df = 0; df < 4; df++) oacc[df][r] *= cc;
      }
      m = mnew;
    }

    u32 own0[8], own1[8], oth0[8], oth1[8];
    float ps = 0.f;
#pragma unroll
    for (int s = 0; s < 8; s++) {
      float a0 = __builtin_amdgcn_exp2f(t0[2 * s] - m);
      float b0 = __builtin_amdgcn_exp2f(t0[2 * s + 1] - m);
      float a1 = __builtin_amdgcn_exp2f(t1[2 * s] - m);
      float b1 = __builtin_amdgcn_exp2f(t1[2 * s + 1] - m);
      ps += (a0 + b0) + (a1 + b1);
      own0[s] = pkbf(a0, b0);
      own1[s] = pkbf(a1, b1);
    }
    ps += __shfl_xor(ps, 32);
    li += ps;
#pragma unroll
    for (int s = 0; s < 8; s++) {
      oth0[s] = (u32)__shfl_xor((int)own0[s], 32);
      oth1[s] = (u32)__shfl_xor((int)own1[s], 32);
    }

#pragma unroll
    for (int ks = 0; ks < 4; ks++) {
      const u32* ow = (ks < 2) ? own0 : own1;
      const u32* ot = (ks < 2) ? oth0 : oth1;
      const int bo = 4 * (ks & 1);
      u32x4 pw;
      pw[0] = hi ? ot[bo + 2] : ow[bo];
      pw[1] = hi ? ot[bo + 3] : ow[bo + 1];
      pw[2] = hi ? ow[bo + 2] : ot[bo];
      pw[3] = hi ? ow[bo + 3] : ot[bo + 1];
      bf16x8 pf = __builtin_bit_cast(bf16x8, pw);
#pragma unroll
      for (int df = 0; df < 4; df++) {
        int d = df * 32 + l31;
        bf16x8 vf = *reinterpret_cast<const bf16x8*>(vb_l + d * 128 + (((ks * 2 + hi) ^ (d & 7)) << 4));
        oacc[df] = __builtin_amdgcn_mfma_f32_32x32x16_bf16(pf, vf, oacc[df], 0, 0, 0);
      }
    }

    __builtin_amdgcn_s_barrier();
    if (c + 2 < nc) stage(c & 1, kc + 128);
  }

#pragma unroll
  for (int r = 0; r < 16; r++) {
    int qrow = (r & 3) + 8 * (r >> 2) + 4 * hi;
    float lsum = __shfl(li, qrow);
    float inv = 1.f / lsum;
    u16* orow = Ab + ((size_t)((b * S_ + qbase + qrow) * H_ + h)) * HD_ + l31;
#pragma unroll
    for (int df = 0; df < 4; df++)
      orow[df * 32] = f2bf(oacc[df][r] * inv);
  }
}

// ---------------- launch ----------------
extern "C" void kernel_launch(void* const* d_in, const int* in_sizes, int n_in,
                              void* d_out, int out_size, void* d_ws, size_t ws_size,
                              hipStream_t stream) {
  const float* x    = (const float*)d_in[0];
  const float* cosp = (const float*)d_in[1];
  const float* sinp = (const float*)d_in[2];
  const float* wq   = (const float*)d_in[3];
  const float* wk   = (const float*)d_in[4];
  const float* wv   = (const float*)d_in[5];
  const float* wo   = (const float*)d_in[6];
  float* out = (float*)d_out;

  char* ws = (char*)d_ws;
  size_t off = 0;
  auto alloc = [&](size_t bytes) -> void* {
    void* p = ws + off;
    off += (bytes + 255) & ~(size_t)255;
    return p;
  };
  u16* xb     = (u16*)alloc((size_t)MQ_ * DIM_ * 2);
  u16* wqkvT  = (u16*)alloc((size_t)NQKV_ * DIM_ * 2);
  u16* woT    = (u16*)alloc((size_t)DIM_ * DIM_ * 2);
  u16* Cq     = (u16*)alloc((size_t)MQ_ * NQKV_ * 2);   // fused QKV (bf16)
  u16* Vt     = (u16*)alloc((size_t)MQ_ * NKV_ * 2);
  u16* Ab     = (u16*)alloc((size_t)MQ_ * DIM_ * 2);

  const int TB = 256;
  cvt_x_kernel<<<(MQ_ * DIM_ / 4 + TB - 1) / TB, TB, 0, stream>>>(x, xb, MQ_ * DIM_ / 4);
  wtT_all_kernel<<<dim3(80, 32), TB, 0, stream>>>(wq, wk, wv, wo, wqkvT, woT);

  // fused QKV projection (bf16 out): 256x256 8-phase, 192 blocks
  gemm256<256, u16><<<dim3(NQKV_ / 256, MQ_ / 256), 512, 0, stream>>>(xb, wqkvT, Cq, MQ_, NQKV_, DIM_);

  // RoPE in-place on Q+K blocks (heads 0..19); V transpose
  rope_bf_kernel<<<(MQ_ * 20 * 64 + TB - 1) / TB, TB, 0, stream>>>(Cq, cosp, sinp, MQ_ * 20 * 64);
  vtT_kernel<<<dim3(S_ / 64, HD_ / 64, B_ * HKV_), TB, 0, stream>>>(Cq, Vt);

  // attention: 512 blocks = 64 q-tiles x 4 groups x 2 batch
  attn_kernel<<<dim3(64 * 8), TB, 0, stream>>>(Cq, Cq + KOFF_, Vt, Ab);

  // output projection -> f32 d_out: 256x128 8-phase, 256 blocks (full CU coverage)
  gemm256<128, float><<<dim3(DIM_ / 128, MQ_ / 256), 512, 0, stream>>>(Ab, woT, out, MQ_, DIM_, DIM_);
}

// Round 11
// 209.980 us; speedup vs baseline: 1.1055x; 1.0002x over previous
//
#include <hip/hip_runtime.h>
#include <cstdint>
#include <cmath>

#define B_ 2
#define S_ 2048
#define DIM_ 2048
#define H_ 16
#define HKV_ 4
#define HD_ 128
#define MQ_ (B_*S_)      // 4096 rows
#define NKV_ (HKV_*HD_)  // 512
#define NQKV_ 3072       // fused QKV output width
#define KOFF_ 2048       // col offset of K block in fused buffer
#define VOFF_ 2560       // col offset of V block

typedef unsigned short u16;
typedef unsigned int u32;
typedef __bf16 bf16_t;
typedef bf16_t bf16x8 __attribute__((ext_vector_type(8)));
typedef bf16_t bf16x2 __attribute__((ext_vector_type(2)));
typedef u16 u16x8 __attribute__((ext_vector_type(8)));
typedef u16 u16x4 __attribute__((ext_vector_type(4)));
typedef float f32x4 __attribute__((ext_vector_type(4)));
typedef float f32x16 __attribute__((ext_vector_type(16)));
typedef u32 u32x4 __attribute__((ext_vector_type(4)));

__device__ __forceinline__ u16 f2bf(float f) {
  union { float f; uint32_t u; } v; v.f = f;
  return (u16)((v.u + 0x7FFFu + ((v.u >> 16) & 1u)) >> 16);
}

__device__ __forceinline__ u32 pkbf(float a, float b) {
  bf16x2 v; v[0] = (bf16_t)a; v[1] = (bf16_t)b;
  return __builtin_bit_cast(u32, v);
}

__device__ __forceinline__ float bf2f(u16 u) {
  union { u32 u; float f; } v; v.u = ((u32)u) << 16;
  return v.f;
}

// ---------------- conversion kernels ----------------

__global__ void cvt_x_kernel(const float* __restrict__ in, u16* __restrict__ out, int n4) {
  int i = blockIdx.x * blockDim.x + threadIdx.x;
  if (i >= n4) return;
  float4 v = reinterpret_cast<const float4*>(in)[i];
  u16x4 o;
  o[0] = f2bf(v.x); o[1] = f2bf(v.y); o[2] = f2bf(v.z); o[3] = f2bf(v.w);
  reinterpret_cast<u16x4*>(out)[i] = o;
}

// All four weight transposes in one launch. grid (80, 32).
__global__ void wtT_all_kernel(const float* __restrict__ wq, const float* __restrict__ wk,
                               const float* __restrict__ wv, const float* __restrict__ wo,
                               u16* __restrict__ wqkvT, u16* __restrict__ woT) {
  __shared__ u16 tile[64][66];
  const int z = blockIdx.x;
  const float* src; u16* dst; int N, n0;
  if (z < 32)      { src = wq; dst = wqkvT;                          N = 2048; n0 = z * 64; }
  else if (z < 40) { src = wk; dst = wqkvT + (size_t)KOFF_ * DIM_;   N = 512;  n0 = (z - 32) * 64; }
  else if (z < 48) { src = wv; dst = wqkvT + (size_t)VOFF_ * DIM_;   N = 512;  n0 = (z - 40) * 64; }
  else             { src = wo; dst = woT;                            N = 2048; n0 = (z - 48) * 64; }
  const int k0 = blockIdx.y * 64;
  const int tx = threadIdx.x & 63, ty = threadIdx.x >> 6;
#pragma unroll
  for (int i = 0; i < 16; i++) {
    int kr = ty + i * 4;
    tile[tx][kr] = f2bf(src[(size_t)(k0 + kr) * N + n0 + tx]);
  }
  __syncthreads();
#pragma unroll
  for (int i = 0; i < 16; i++) {
    int nr = ty + i * 4;
    dst[(size_t)(n0 + nr) * DIM_ + k0 + tx] = tile[nr][tx];
  }
}

// RoPE in-place on bf16 fused-QKV buffer; heads 0..15 = Q, 16..19 = K.
__global__ void rope_bf_kernel(u16* __restrict__ buf, const float* __restrict__ cosp,
                               const float* __restrict__ sinp, int npairs) {
  int i = blockIdx.x * blockDim.x + threadIdx.x;
  if (i >= npairs) return;
  int j = i & 63;
  int head = (i >> 6) % 20;
  int token = i / (20 * 64);
  int s = token % S_;
  u16* p = buf + (size_t)token * NQKV_ + head * HD_ + j * 2;
  u32 v = *reinterpret_cast<u32*>(p);
  float t0 = bf2f((u16)(v & 0xFFFF));
  float t1 = bf2f((u16)(v >> 16));
  float c = cosp[s * 64 + j], sn = sinp[s * 64 + j];
  u16 lo = f2bf(t0 * c - t1 * sn);
  u16 hi = f2bf(t0 * sn + t1 * c);
  *reinterpret_cast<u32*>(p) = (u32)lo | ((u32)hi << 16);
}

// Tiled transpose V: fused buf col VOFF_.. -> Vt [b][g][d][s]
__global__ void vtT_kernel(const u16* __restrict__ qkv, u16* __restrict__ vt) {
  __shared__ u16 tile[64][66];
  const int s0 = blockIdx.x * 64, d0 = blockIdx.y * 64;
  const int bg = blockIdx.z, b = bg >> 2, g = bg & 3;
  const int tx = threadIdx.x & 63, ty = threadIdx.x >> 6;
#pragma unroll
  for (int i = 0; i < 16; i++) {
    int sr = ty + i * 4;
    tile[tx][sr] = qkv[(size_t)(b * S_ + s0 + sr) * NQKV_ + VOFF_ + g * HD_ + d0 + tx];
  }
  __syncthreads();
#pragma unroll
  for (int i = 0; i < 16; i++) {
    int dr = ty + i * 4;
    vt[((size_t)bg * HD_ + d0 + dr) * S_ + s0 + tx] = tile[dr][tx];
  }
}

// ---------------- 256xBN 8-phase GEMM (BN in {256,128}) ----------------
// C(MxN) = A(bf16 MxK) x Bt(bf16 NxK)^T. 512 threads = 8 waves.
// BN=256: waves 2M x 4N, per-wave 128x64. BN=128: waves 4M x 2N, per-wave 64x64.
// BK=64, 2 K-tiles/iter. 3-bit slot swizzle (slot ^= row&7), pre-swizzled source.
// Counted vmcnt(2) at phases 4/8 only (per-tile outstanding ops: 2 newest allowed).
template <int BN, typename OutT>
__launch_bounds__(512, 1)
__global__ void gemm256(const u16* __restrict__ A, const u16* __restrict__ Bt,
                        OutT* __restrict__ C, int M, int N, int K) {
  constexpr int NWN = BN / 64;        // N-waves (4 or 2)
  constexpr int NWM = 8 / NWN;        // M-waves (2 or 4)
  constexpr int RW  = 256 / NWM;      // rows per wave (128 or 64)
  constexpr int RH  = RW / 2;         // rows per mh half (64 or 32)
  constexpr int MFR = RH / 16;        // m-frags per half (4 or 2)
  constexpr int BHB = BN * 64;        // B half bytes (16384 or 8192)
  constexpr int BST = BHB / 8192;     // B stage steps (2 or 1)

  __shared__ u16 As[2][16384];        // 256 rows x 64 cols
  __shared__ u16 Bs[2][BN * 64];
  const int tid = threadIdx.x;
  const int lane = tid & 63, wid = tid >> 6;
  const int lr = lane & 15, lg = lane >> 4;
  const int wm = (wid / NWN) * RW;
  const int wn = (wid % NWN) * 64;
  const int m0 = blockIdx.y * 256, n0 = blockIdx.x * BN;
  const u16* Atile = A + (size_t)m0 * K;
  const u16* Btile = Bt + (size_t)n0 * K;
  const int NT = K >> 6;
  const int NIT = NT >> 1;

  f32x4 acc[2 * MFR][4] = {};
  bf16x8 afr[MFR][2];
  bf16x8 bfr[2][2][2];

  auto stgA = [&](u16* lbase, int t, int h) {
#pragma unroll
    for (int j = 0; j < 2; j++) {
      int L = (tid + j * 512) * 16;
      int r = L >> 7;
      int slot = (L >> 4) & 7;
      int c = (slot ^ (r & 7)) << 4;
      const char* src = (const char*)(Atile + (size_t)(h * 128 + r) * K + t * 64) + c;
      __builtin_amdgcn_global_load_lds(
          (const __attribute__((address_space(1))) unsigned int*)src,
          (__attribute__((address_space(3))) unsigned int*)((char*)lbase + h * 16384 + L),
          16, 0, 0);
    }
  };
  auto stgB = [&](u16* lbase, int t, int h) {
#pragma unroll
    for (int j = 0; j < BST; j++) {
      int L = (tid + j * 512) * 16;
      int r = L >> 7;
      int slot = (L >> 4) & 7;
      int c = (slot ^ (r & 7)) << 4;
      const char* src = (const char*)(Btile + (size_t)(h * (BN / 2) + r) * K + t * 64) + c;
      __builtin_amdgcn_global_load_lds(
          (const __attribute__((address_space(1))) unsigned int*)src,
          (__attribute__((address_space(3))) unsigned int*)((char*)lbase + h * BHB + L),
          16, 0, 0);
    }
  };
  auto lds8 = [&](const u16* lbase, int r, int cb) -> bf16x8 {
    int slot = (cb >> 4) & 7;
    int L = r * 128 + ((slot ^ (r & 7)) << 4) + (cb & 15);
    return *reinterpret_cast<const bf16x8*>((const char*)lbase + L);
  };
  auto readA = [&](int buf, int mh) {
#pragma unroll
    for (int im = 0; im < MFR; im++)
#pragma unroll
      for (int k = 0; k < 2; k++)
        afr[im][k] = lds8(As[buf], wm + mh * RH + im * 16 + lr, k * 64 + lg * 16);
  };
  auto readB = [&](int buf, int nh) {
#pragma unroll
    for (int jn = 0; jn < 2; jn++)
#pragma unroll
      for (int k = 0; k < 2; k++)
        bfr[nh][jn][k] = lds8(Bs[buf], wn + nh * 32 + jn * 16 + lr, k * 64 + lg * 16);
  };
  auto quad = [&](int mh, int nh) {
    __builtin_amdgcn_s_setprio(1);
#pragma unroll
    for (int im = 0; im < MFR; im++)
#pragma unroll
      for (int jn = 0; jn < 2; jn++)
#pragma unroll
      for (int k = 0; k < 2; k++)
        acc[mh * MFR + im][nh * 2 + jn] = __builtin_amdgcn_mfma_f32_16x16x32_bf16(
            afr[im][k], bfr[nh][jn][k], acc[mh * MFR + im][nh * 2 + jn], 0, 0, 0);
    __builtin_amdgcn_s_setprio(0);
  };
  auto bar = [&]() {
    asm volatile("" ::: "memory");
    __builtin_amdgcn_s_barrier();
    asm volatile("" ::: "memory");
  };

  // prologue: tile0 fully, then S1(t1)=A h0 -> buf1; wait tile0
  stgA(As[0], 0, 0); stgA(As[0], 0, 1);
  stgB(Bs[0], 0, 0); stgB(Bs[0], 0, 1);
  stgA(As[1], 1, 0);
  asm volatile("s_waitcnt vmcnt(2)" ::: "memory");
  __builtin_amdgcn_s_barrier();

  for (int it = 0; it < NIT; ++it) {
    const int ta = 2 * it, tb = ta + 1;
    const bool sA = (ta + 2 < NT);
    const bool sB = (tb + 2 < NT);

    readA(0, 0); readB(0, 0);
    stgA(As[1], tb, 1);
    bar(); quad(0, 0); bar();
    readB(0, 1);
    stgB(Bs[1], tb, 0);
    bar(); quad(0, 1); bar();
    readA(0, 1);
    stgB(Bs[1], tb, 1);
    bar(); quad(1, 1); bar();
    if (sA) stgA(As[0], ta + 2, 0);
    bar(); quad(1, 0);
    if (sA) asm volatile("s_waitcnt vmcnt(2)" ::: "memory");
    else    asm volatile("s_waitcnt vmcnt(0)" ::: "memory");
    bar();

    readA(1, 0); readB(1, 0);
    if (sA) stgA(As[0], ta + 2, 1);
    bar(); quad(0, 0); bar();
    readB(1, 1);
    if (sA) stgB(Bs[0], ta + 2, 0);
    bar(); quad(0, 1); bar();
    readA(1, 1);
    if (sA) stgB(Bs[0], ta + 2, 1);
    bar(); quad(1, 1); bar();
    if (sB) stgA(As[1], tb + 2, 0);
    bar(); quad(1, 0);
    if (sA) {
      if (sB) asm volatile("s_waitcnt vmcnt(2)" ::: "memory");
      else    asm volatile("s_waitcnt vmcnt(0)" ::: "memory");
    }
    bar();
  }

#pragma unroll
  for (int i = 0; i < 2 * MFR; i++)
#pragma unroll
    for (int j = 0; j < 4; j++)
#pragma unroll
      for (int rr = 0; rr < 4; rr++) {
        int row = m0 + wm + (i / MFR) * RH + (i % MFR) * 16 + lg * 4 + rr;
        int col = n0 + wn + (j >> 1) * 32 + (j & 1) * 16 + lr;
        if constexpr (__is_same(OutT, float))
          C[(size_t)row * N + col] = acc[i][j][rr];
        else
          C[(size_t)row * N + col] = f2bf(acc[i][j][rr]);
      }
}

// ---------------- flash attention (round-7 exact: best measured 83 us) ----------------
__launch_bounds__(256, 2)
__global__ void attn_kernel(const u16* __restrict__ Qc, const u16* __restrict__ Kc,
                            const u16* __restrict__ Vt, u16* __restrict__ Ab) {
  __shared__ u16 Ks[2][64 * 128];   // [key][d] 256B rows, 16-slot swizzle
  __shared__ u16 Vs[2][128 * 64];   // [d][key] 128B rows, 8-slot swizzle

  const int bk = blockIdx.x;
  const int i = bk >> 3, gb = bk & 7;
  const int g = gb & 3, b = gb >> 2;
  const int qt = (i < 32) ? (63 - i) : (i - 32);  // heavy-first, complementary pairs
  const int w = threadIdx.x >> 6, lane = threadIdx.x & 63;
  const int l31 = lane & 31, hi = lane >> 5;
  const int h = g * 4 + w;                        // wave = head within group
  const int qbase = qt * 32;
  const int qi = qbase + l31;
  const float k1 = 0.08838834764831845f * 1.4426950408889634f; // scale*log2e

  bf16x8 qf[8];
  const u16* qptr = Qc + (size_t)(b * S_ + qi) * NQKV_ + h * HD_ + hi * 8;
#pragma unroll
  for (int dk = 0; dk < 8; dk++)
    qf[dk] = *reinterpret_cast<const bf16x8*>(qptr + dk * 16);

  f32x16 oacc[4] = {};
  float m = -INFINITY, li = 0.f;

  const char* kgb = (const char*)(Kc + (size_t)b * S_ * NQKV_ + g * HD_);
  const char* vgb = (const char*)(Vt + ((size_t)(b * HKV_ + g) * HD_) * (size_t)S_);
  const int nc = (qt >> 1) + 1;

  auto stage = [&](int buf, int kc) {
#pragma unroll
    for (int j = 0; j < 4; j++) {            // K: 16KB, wave's 4x1KB slices
      int L = (w * 4 + j) * 1024 + lane * 16;
      int key = L >> 8;
      int slot = (L >> 4) & 15;
      const char* src = kgb + (size_t)(kc + key) * (NQKV_ * 2) + ((slot ^ (key & 15)) << 4);
      __builtin_amdgcn_global_load_lds(
          (const __attribute__((address_space(1))) unsigned int*)src,
          (__attribute__((address_space(3))) unsigned int*)((char*)&Ks[buf][0] + (w * 4 + j) * 1024),
          16, 0, 0);
    }
#pragma unroll
    for (int j = 0; j < 4; j++) {            // V: 16KB
      int L = (w * 4 + j) * 1024 + lane * 16;
      int d = L >> 7;
      int slot = (L >> 4) & 7;
      const char* src = vgb + ((size_t)d * S_ + kc) * 2 + ((slot ^ (d & 7)) << 4);
      __builtin_amdgcn_global_load_lds(
          (const __attribute__((address_space(1))) unsigned int*)src,
          (__attribute__((address_space(3))) unsigned int*)((char*)&Vs[buf][0] + (w * 4 + j) * 1024),
          16, 0, 0);
    }
  };

  stage(0, 0);
  if (nc > 1) stage(1, 64);

  for (int c = 0; c < nc; ++c) {
    if (c + 1 < nc) asm volatile("s_waitcnt vmcnt(8)" ::: "memory");
    else            asm volatile("s_waitcnt vmcnt(0)" ::: "memory");
    __builtin_amdgcn_s_barrier();

    const char* kb_l = (const char*)&Ks[c & 1][0];
    const char* vb_l = (const char*)&Vs[c & 1][0];
    const int kc = c * 64;

    f32x16 sa0 = {}, sa1 = {};
#pragma unroll
    for (int dk = 0; dk < 8; dk++) {
      bf16x8 kf0 = *reinterpret_cast<const bf16x8*>(kb_l + l31 * 256 + (((dk * 2 + hi) ^ (l31 & 15)) << 4));
      sa0 = __builtin_amdgcn_mfma_f32_32x32x16_bf16(kf0, qf[dk], sa0, 0, 0, 0);
    }
#pragma unroll
    for (int dk = 0; dk < 8; dk++) {
      int key1 = 32 + l31;
      bf16x8 kf1 = *reinterpret_cast<const bf16x8*>(kb_l + key1 * 256 + (((dk * 2 + hi) ^ (key1 & 15)) << 4));
      sa1 = __builtin_amdgcn_mfma_f32_32x32x16_bf16(kf1, qf[dk], sa1, 0, 0, 0);
    }

    float t0[16], t1[16];
    const bool edge = (kc + 63 > qbase);
#pragma unroll
    for (int r = 0; r < 16; r++) {
      int kl = (r & 3) + 8 * (r >> 2) + 4 * hi;
      float v0 = sa0[r] * k1;
      float v1 = sa1[r] * k1;
      if (edge) {
        v0 = (kc + kl <= qi) ? v0 : -INFINITY;
        v1 = (kc + 32 + kl <= qi) ? v1 : -INFINITY;
      }
      t0[r] = v0; t1[r] = v1;
    }

    float mx[8];
#pragma unroll
    for (int r = 0; r < 8; r++)
      mx[r] = fmaxf(fmaxf(t0[r], t0[r + 8]), fmaxf(t1[r], t1[r + 8]));
    mx[0] = fmaxf(mx[0], mx[4]); mx[1] = fmaxf(mx[1], mx[5]);
    mx[2] = fmaxf(mx[2], mx[6]); mx[3] = fmaxf(mx[3], mx[7]);
    mx[0] = fmaxf(fmaxf(mx[0], mx[1]), fmaxf(mx[2], mx[3]));
    float tm = fmaxf(mx[0], __shfl_xor(mx[0], 32));

    if (!__all(tm <= m + 8.f)) {               // defer-max (T13)
      float mnew = fmaxf(m, tm);
      float corr = __builtin_amdgcn_exp2f(m - mnew);
      li *= corr;
#pragma unroll
      for (int r = 0; r < 16; r++) {
        float cc = __shfl(corr, (r & 3) + 8 * (r >> 2) + 4 * hi);
#pragma unroll
        for (int df = 0; df < 4; df++) oacc[df][r] *= cc;
      }
      m = mnew;
    }

    u32 own0[8], own1[8], oth0[8], oth1[8];
    float ps = 0.f;
#pragma unroll
    for (int s = 0; s < 8; s++) {
      float a0 = __builtin_amdgcn_exp2f(t0[2 * s] - m);
      float b0 = __builtin_amdgcn_exp2f(t0[2 * s + 1] - m);
      float a1 = __builtin_amdgcn_exp2f(t1[2 * s] - m);
      float b1 = __builtin_amdgcn_exp2f(t1[2 * s + 1] - m);
      ps += (a0 + b0) + (a1 + b1);
      own0[s] = pkbf(a0, b0);
      own1[s] = pkbf(a1, b1);
    }
    ps += __shfl_xor(ps, 32);
    li += ps;
#pragma unroll
    for (int s = 0; s < 8; s++) {
      oth0[s] = (u32)__shfl_xor((int)own0[s], 32);
      oth1[s] = (u32)__shfl_xor((int)own1[s], 32);
    }

#pragma unroll
    for (int ks = 0; ks < 4; ks++) {
      const u32* ow = (ks < 2) ? own0 : own1;
      const u32* ot = (ks < 2) ? oth0 : oth1;
      const int bo = 4 * (ks & 1);
      u32x4 pw;
      pw[0] = hi ? ot[bo + 2] : ow[bo];
      pw[1] = hi ? ot[bo + 3] : ow[bo + 1];
      pw[2] = hi ? ow[bo + 2] : ot[bo];
      pw[3] = hi ? ow[bo + 3] : ot[bo + 1];
      bf16x8 pf = __builtin_bit_cast(bf16x8, pw);
#pragma unroll
      for (int df = 0; df < 4; df++) {
        int d = df * 32 + l31;
        bf16x8 vf = *reinterpret_cast<const bf16x8*>(vb_l + d * 128 + (((ks * 2 + hi) ^ (d & 7)) << 4));
        oacc[df] = __builtin_amdgcn_mfma_f32_32x32x16_bf16(pf, vf, oacc[df], 0, 0, 0);
      }
    }

    __builtin_amdgcn_s_barrier();
    if (c + 2 < nc) stage(c & 1, kc + 128);
  }

#pragma unroll
  for (int r = 0; r < 16; r++) {
    int qrow = (r & 3) + 8 * (r >> 2) + 4 * hi;
    float lsum = __shfl(li, qrow);
    float inv = 1.f / lsum;
    u16* orow = Ab + ((size_t)((b * S_ + qbase + qrow) * H_ + h)) * HD_ + l31;
#pragma unroll
    for (int df = 0; df < 4; df++)
      orow[df * 32] = f2bf(oacc[df][r] * inv);
  }
}

// ---------------- launch ----------------
extern "C" void kernel_launch(void* const* d_in, const int* in_sizes, int n_in,
                              void* d_out, int out_size, void* d_ws, size_t ws_size,
                              hipStream_t stream) {
  const float* x    = (const float*)d_in[0];
  const float* cosp = (const float*)d_in[1];
  const float* sinp = (const float*)d_in[2];
  const float* wq   = (const float*)d_in[3];
  const float* wk   = (const float*)d_in[4];
  const float* wv   = (const float*)d_in[5];
  const float* wo   = (const float*)d_in[6];
  float* out = (float*)d_out;

  char* ws = (char*)d_ws;
  size_t off = 0;
  auto alloc = [&](size_t bytes) -> void* {
    void* p = ws + off;
    off += (bytes + 255) & ~(size_t)255;
    return p;
  };
  u16* xb     = (u16*)alloc((size_t)MQ_ * DIM_ * 2);
  u16* wqkvT  = (u16*)alloc((size_t)NQKV_ * DIM_ * 2);
  u16* woT    = (u16*)alloc((size_t)DIM_ * DIM_ * 2);
  u16* Cq     = (u16*)alloc((size_t)MQ_ * NQKV_ * 2);   // fused QKV (bf16)
  u16* Vt     = (u16*)alloc((size_t)MQ_ * NKV_ * 2);
  u16* Ab     = (u16*)alloc((size_t)MQ_ * DIM_ * 2);

  const int TB = 256;
  cvt_x_kernel<<<(MQ_ * DIM_ / 4 + TB - 1) / TB, TB, 0, stream>>>(x, xb, MQ_ * DIM_ / 4);
  wtT_all_kernel<<<dim3(80, 32), TB, 0, stream>>>(wq, wk, wv, wo, wqkvT, woT);

  // fused QKV projection (bf16 out): 256x256 8-phase, 192 blocks
  gemm256<256, u16><<<dim3(NQKV_ / 256, MQ_ / 256), 512, 0, stream>>>(xb, wqkvT, Cq, MQ_, NQKV_, DIM_);

  // RoPE in-place on Q+K blocks (heads 0..19); V transpose
  rope_bf_kernel<<<(MQ_ * 20 * 64 + TB - 1) / TB, TB, 0, stream>>>(Cq, cosp, sinp, MQ_ * 20 * 64);
  vtT_kernel<<<dim3(S_ / 64, HD_ / 64, B_ * HKV_), TB, 0, stream>>>(Cq, Vt);

  // attention: 512 blocks = 64 q-tiles x 4 groups x 2 batch
  attn_kernel<<<dim3(64 * 8), TB, 0, stream>>>(Cq, Cq + KOFF_, Vt, Ab);

  // output projection -> f32 d_out: 256x128 8-phase, 256 blocks (full CU coverage)
  gemm256<128, float><<<dim3(DIM_ / 128, MQ_ / 256), 512, 0, stream>>>(Ab, woT, out, MQ_, DIM_, DIM_);
}